// Round 7
// baseline (162.434 us; speedup 1.0000x reference)
//
#include <hip/hip_runtime.h>
#include <hip/hip_bf16.h>

// Head: B=8, T=2048, D=1024, H=64, fp32 in/out.
#define BB 8
#define TT 2048
#define DD 1024
#define HH 64
#define NROWS (BB*TT)
#define SCALE 45.25483399593904f   // sqrt(2048)
#define SPLIT 4                    // flash split-K factor

typedef __attribute__((ext_vector_type(8))) short short8;
typedef __attribute__((ext_vector_type(4))) float f32x4;

__device__ inline ushort bf16rne(float f) {
    unsigned u = __float_as_uint(f);
    return (ushort)((u + 0x7fffu + ((u >> 16) & 1u)) >> 16);
}
__device__ inline void bfsplit(float f, ushort& hi, ushort& lo) {
    hi = bf16rne(f);
    float fh = __uint_as_float(((unsigned)hi) << 16);
    lo = bf16rne(f - fh);
}
__device__ inline void split_pack8(const float* v, int4& h4, int4& l4) {
    ushort h[8], l[8];
    #pragma unroll
    for (int j = 0; j < 8; ++j) bfsplit(v[j], h[j], l[j]);
    h4 = make_int4((int)(h[0] | ((unsigned)h[1] << 16)), (int)(h[2] | ((unsigned)h[3] << 16)),
                   (int)(h[4] | ((unsigned)h[5] << 16)), (int)(h[6] | ((unsigned)h[7] << 16)));
    l4 = make_int4((int)(l[0] | ((unsigned)l[1] << 16)), (int)(l[2] | ((unsigned)l[3] << 16)),
                   (int)(l[4] | ((unsigned)l[5] << 16)), (int)(l[6] | ((unsigned)l[7] << 16)));
}

// ---------------------------------------------------------------------------
// Kernel P: W prep (unchanged from r4). Pre-swizzled chunk-major bf16 hi/lo.
// ---------------------------------------------------------------------------
__global__ __launch_bounds__(256) void wprep_kernel(
        const float* __restrict__ Wq, const float* __restrict__ Wk,
        const float* __restrict__ Wv,
        ushort* __restrict__ WpHi, ushort* __restrict__ WpLo) {
    __shared__ float ws[64 * 65];
    const int m = blockIdx.x >> 4;      // matrix 0..2
    const int c = blockIdx.x & 15;      // k-chunk 0..15
    const float* W = (m == 0) ? Wq : (m == 1) ? Wk : Wv;
    const int tid = threadIdx.x;

    #pragma unroll
    for (int p = 0; p < 4; ++p) {
        int i = tid + p * 256;
        int r = i >> 4, q4 = i & 15;
        float4 v = *(const float4*)(W + (size_t)(c * 64 + r) * 64 + q4 * 4);
        ws[r * 65 + q4 * 4 + 0] = v.x;
        ws[r * 65 + q4 * 4 + 1] = v.y;
        ws[r * 65 + q4 * 4 + 2] = v.z;
        ws[r * 65 + q4 * 4 + 3] = v.w;
    }
    __syncthreads();

    #pragma unroll
    for (int p = 0; p < 2; ++p) {
        int gi = tid + p * 256;
        int nn = gi >> 3, g8 = gi & 7;
        int o  = g8 ^ (nn & 7);
        float v[8];
        #pragma unroll
        for (int j = 0; j < 8; ++j) v[j] = ws[(o * 8 + j) * 65 + nn];
        int4 h4, l4; split_pack8(v, h4, l4);
        size_t base = (size_t)c * 12288 + (size_t)(m * 64 + nn) * 64 + g8 * 8;
        *(int4*)(WpHi + base) = h4;
        *(int4*)(WpLo + base) = l4;
    }
}

// ---------------------------------------------------------------------------
// Kernel A: QKV via MFMA 16x16x32 bf16, 3-pass split precision.
// BM=32 => 512 blocks = 2 blocks/CU = 8 waves/CU; blocks interleave barriers.
// ---------------------------------------------------------------------------
__global__ __launch_bounds__(256) void qkv_kernel(
        const float* __restrict__ x,
        const ushort* __restrict__ WpHi, const ushort* __restrict__ WpLo,
        float* __restrict__ Qo, ushort* __restrict__ KhiP,
        ushort* __restrict__ KloP, ushort* __restrict__ VtP) {
    __shared__ ushort Ahi[32 * 64], Alo[32 * 64];     // 4 KiB each
    __shared__ ushort Bhi[192 * 64], Blo[192 * 64];   // 24 KiB each
    const int tid  = threadIdx.x;
    const int lane = tid & 63;
    const int w    = tid >> 6;
    const int n15  = lane & 15;
    const int g    = lane >> 4;
    const int csw  = n15 & 7;
    const int row0 = blockIdx.x * 32;

    f32x4 acc[2][3];
    #pragma unroll
    for (int ms = 0; ms < 2; ++ms)
        #pragma unroll
        for (int nt = 0; nt < 3; ++nt) acc[ms][nt] = (f32x4)0.f;

    for (int c = 0; c < 16; ++c) {
        __syncthreads();
        // ---- stage A: 32 rows x 64 k -> bf16 hi/lo, swizzled ----
        {
            int r = tid >> 3, oc = tid & 7;
            const float* src = x + (size_t)(row0 + r) * 1024 + c * 64 + oc * 8;
            float v[8];
            *(float4*)v       = *(const float4*)src;
            *(float4*)(v + 4) = *(const float4*)(src + 4);
            int4 h4, l4; split_pack8(v, h4, l4);
            int di = r * 64 + ((oc ^ (r & 7)) << 3);
            *(int4*)&Ahi[di] = h4;
            *(int4*)&Alo[di] = l4;
        }
        // ---- stage B: pre-swizzled in global -> linear copy ----
        {
            const int4* sh = (const int4*)(WpHi + (size_t)c * 12288);
            const int4* sl = (const int4*)(WpLo + (size_t)c * 12288);
            int4* dh = (int4*)Bhi;
            int4* dl = (int4*)Blo;
            #pragma unroll
            for (int p = 0; p < 6; ++p) {
                int gi = tid + p * 256;
                dh[gi] = sh[gi];
                dl[gi] = sl[gi];
            }
        }
        __syncthreads();

        #pragma unroll
        for (int kh = 0; kh < 2; ++kh) {
            short8 afh[2], afl[2], bfh[3], bfl[3];
            #pragma unroll
            for (int ms = 0; ms < 2; ++ms) {
                int ridx = (ms * 16 + n15) * 64 + (((4 * kh + g) ^ csw) << 3);
                afh[ms] = *(const short8*)&Ahi[ridx];
                afl[ms] = *(const short8*)&Alo[ridx];
            }
            #pragma unroll
            for (int nt = 0; nt < 3; ++nt) {
                int nr = w * 48 + nt * 16 + n15;
                int ridx = nr * 64 + (((4 * kh + g) ^ csw) << 3);
                bfh[nt] = *(const short8*)&Bhi[ridx];
                bfl[nt] = *(const short8*)&Blo[ridx];
            }
            #pragma unroll
            for (int nt = 0; nt < 3; ++nt)
                #pragma unroll
                for (int ms = 0; ms < 2; ++ms) {
                    acc[ms][nt] = __builtin_amdgcn_mfma_f32_16x16x32_bf16(
                        afh[ms], bfh[nt], acc[ms][nt], 0, 0, 0);
                    acc[ms][nt] = __builtin_amdgcn_mfma_f32_16x16x32_bf16(
                        afl[ms], bfh[nt], acc[ms][nt], 0, 0, 0);
                    acc[ms][nt] = __builtin_amdgcn_mfma_f32_16x16x32_bf16(
                        afh[ms], bfl[nt], acc[ms][nt], 0, 0, 0);
                }
        }
    }

    const int b  = row0 >> 11;
    const int t0 = row0 & 2047;
    #pragma unroll
    for (int nt = 0; nt < 3; ++nt) {
        const int nglob = w * 48 + nt * 16 + n15;
        const int mat = nglob >> 6;     // wave-uniform
        const int h = nglob & 63;
        #pragma unroll
        for (int ms = 0; ms < 2; ++ms) {
            const int mb = row0 + ms * 16 + 4 * g;
            if (mat == 0) {
                #pragma unroll
                for (int r = 0; r < 4; ++r)
                    Qo[(size_t)(mb + r) * 64 + h] = acc[ms][nt][r];
            } else if (mat == 1) {
                #pragma unroll
                for (int r = 0; r < 4; ++r) {
                    ushort hi, lo; bfsplit(acc[ms][nt][r], hi, lo);
                    KhiP[(size_t)(mb + r) * 64 + h] = hi;
                    KloP[(size_t)(mb + r) * 64 + h] = lo;
                }
            } else {
                ushort pk[4];
                #pragma unroll
                for (int r = 0; r < 4; ++r) pk[r] = bf16rne(acc[ms][nt][r]);
                const int tloc = t0 + ms * 16 + 4 * g;
                *(uint2*)&VtP[((size_t)(b * 64 + h)) * 2048 + tloc] =
                    make_uint2(pk[0] | ((unsigned)pk[1] << 16),
                               pk[2] | ((unsigned)pk[3] << 16));
            }
        }
    }
}

// ---------------------------------------------------------------------------
// Kernel B: causal flash attention, MFMA, ZERO LDS / ZERO barriers.
// K/V per batch = 768KB -> L2-resident; fragments straight from global.
// Split-K x4 for occupancy (2048 blocks = 16 waves/CU) and tail balance.
// ---------------------------------------------------------------------------
__global__ __launch_bounds__(128) void attn_kernel(
        const float* __restrict__ Q, const ushort* __restrict__ Khi,
        const ushort* __restrict__ Klo, const ushort* __restrict__ Vt,
        float* __restrict__ Pacc, float* __restrict__ Pm,
        float* __restrict__ Pl) {
    const int tid  = threadIdx.x;
    const int lane = tid & 63;
    const int w    = tid >> 6;
    const int n    = lane & 15;
    const int g    = lane >> 4;
    const int b    = blockIdx.y;
    const int xx   = blockIdx.x;            // 0..255, heavy-first
    const int qt   = 63 - (xx >> 2);
    const int sp   = xx & 3;
    const int q0   = qt * 32;
    const int qmin = q0 + w * 16;
    const int qrow = qmin + n;
    const int ntiles = (q0 >> 6) + 1;
    const int it0  = (ntiles * sp) >> 2;    // last split always owns diagonal
    const int it1  = (ntiles * (sp + 1)) >> 2;

    short8 qhi0, qhi1, qlo0, qlo1;
    {
        const float* qp = Q + ((size_t)b * TT + qrow) * HH + 8 * g;
        float v0[8], v1[8];
        *(float4*)(v0)     = *(const float4*)(qp);
        *(float4*)(v0 + 4) = *(const float4*)(qp + 4);
        *(float4*)(v1)     = *(const float4*)(qp + 32);
        *(float4*)(v1 + 4) = *(const float4*)(qp + 36);
        #pragma unroll
        for (int j = 0; j < 8; ++j) {
            ushort hi, lo;
            bfsplit(v0[j], hi, lo); qhi0[j] = (short)hi; qlo0[j] = (short)lo;
            bfsplit(v1[j], hi, lo); qhi1[j] = (short)hi; qlo1[j] = (short)lo;
        }
    }

    f32x4 accO[4];
    #pragma unroll
    for (int t = 0; t < 4; ++t) accO[t] = (f32x4)0.f;
    float m = -1e30f, l = 0.f;

    const ushort* gkh = Khi + (size_t)b * TT * HH;
    const ushort* gkl = Klo + (size_t)b * TT * HH;
    const ushort* gvt = Vt + (size_t)b * 64 * TT;

    for (int it = it0; it < it1; ++it) {
        const int kb = it * 64;

        f32x4 s4[4];
        #pragma unroll
        for (int s = 0; s < 4; ++s) {
            const size_t ro = (size_t)(kb + 16 * s + n) * HH;
            short8 kh0 = *(const short8*)(gkh + ro + 8 * g);
            short8 kh1 = *(const short8*)(gkh + ro + 32 + 8 * g);
            short8 kl0 = *(const short8*)(gkl + ro + 8 * g);
            short8 kl1 = *(const short8*)(gkl + ro + 32 + 8 * g);
            f32x4 a = (f32x4)0.f;
            a = __builtin_amdgcn_mfma_f32_16x16x32_bf16(kh0, qhi0, a, 0, 0, 0);
            a = __builtin_amdgcn_mfma_f32_16x16x32_bf16(kh1, qhi1, a, 0, 0, 0);
            a = __builtin_amdgcn_mfma_f32_16x16x32_bf16(kl0, qhi0, a, 0, 0, 0);
            a = __builtin_amdgcn_mfma_f32_16x16x32_bf16(kl1, qhi1, a, 0, 0, 0);
            a = __builtin_amdgcn_mfma_f32_16x16x32_bf16(kh0, qlo0, a, 0, 0, 0);
            a = __builtin_amdgcn_mfma_f32_16x16x32_bf16(kh1, qlo1, a, 0, 0, 0);
            s4[s] = a;
        }

        float sm[16];
        if (kb + 63 > qmin) {               // only true for the diagonal tile
            #pragma unroll
            for (int s = 0; s < 4; ++s)
                #pragma unroll
                for (int r = 0; r < 4; ++r) {
                    int keyg = kb + 16 * s + 4 * g + r;
                    sm[s * 4 + r] = (keyg <= qrow) ? s4[s][r] * SCALE : -1e30f;
                }
        } else {
            #pragma unroll
            for (int s = 0; s < 4; ++s)
                #pragma unroll
                for (int r = 0; r < 4; ++r) sm[s * 4 + r] = s4[s][r] * SCALE;
        }
        float pm = sm[0];
        #pragma unroll
        for (int i = 1; i < 16; ++i) pm = fmaxf(pm, sm[i]);
        pm = fmaxf(pm, __shfl_xor(pm, 16));
        pm = fmaxf(pm, __shfl_xor(pm, 32));
        float mn = fmaxf(m, pm);
        float es = __expf(m - mn);
        float p[16], ps = 0.f;
        #pragma unroll
        for (int i = 0; i < 16; ++i) { p[i] = __expf(sm[i] - mn); ps += p[i]; }
        ps += __shfl_xor(ps, 16);
        ps += __shfl_xor(ps, 32);
        l = l * es + ps;
        m = mn;
        #pragma unroll
        for (int t = 0; t < 4; ++t)
            #pragma unroll
            for (int r = 0; r < 4; ++r) accO[t][r] *= es;

        short8 pf0, pf1;
        #pragma unroll
        for (int j = 0; j < 4; ++j) {
            pf0[j]     = (short)bf16rne(p[0 * 4 + j]);
            pf0[j + 4] = (short)bf16rne(p[1 * 4 + j]);
            pf1[j]     = (short)bf16rne(p[2 * 4 + j]);
            pf1[j + 4] = (short)bf16rne(p[3 * 4 + j]);
        }

        #pragma unroll
        for (int t = 0; t < 4; ++t) {
            const ushort* vb = gvt + (size_t)(16 * t + n) * TT + kb;
            union { int2 d[2]; short8 v; } u0, u1;
            u0.d[0] = *(const int2*)(vb + 4 * g);
            u0.d[1] = *(const int2*)(vb + 16 + 4 * g);
            u1.d[0] = *(const int2*)(vb + 32 + 4 * g);
            u1.d[1] = *(const int2*)(vb + 48 + 4 * g);
            accO[t] = __builtin_amdgcn_mfma_f32_16x16x32_bf16(u0.v, pf0, accO[t], 0, 0, 0);
            accO[t] = __builtin_amdgcn_mfma_f32_16x16x32_bf16(u1.v, pf1, accO[t], 0, 0, 0);
        }
    }

    // ---- write partials (unnormalized); f32x4 store (r6 fix: was float4=) --
    const size_t brow = (size_t)b * TT + qrow;
    float* pa = Pacc + ((size_t)sp * NROWS + brow) * 64 + 4 * g;
    #pragma unroll
    for (int t = 0; t < 4; ++t)
        *(f32x4*)(pa + 16 * t) = accO[t];
    if (g == 0) {
        Pm[(size_t)sp * NROWS + brow] = m;
        Pl[(size_t)sp * NROWS + brow] = l;
    }
}

// ---------------------------------------------------------------------------
// Kernel C: merge SPLIT partials per (row, h-range).
// out = sum_s exp(m_s - M) accO_s / sum_s exp(m_s - M) l_s.
// ---------------------------------------------------------------------------
__global__ __launch_bounds__(256) void combine_kernel(
        const float* __restrict__ Pacc, const float* __restrict__ Pm,
        const float* __restrict__ Pl, float* __restrict__ out) {
    const int u    = blockIdx.x * 256 + threadIdx.x;   // 0..65535
    const int row  = u >> 2;
    const int quad = u & 3;

    float ms[SPLIT], ls[SPLIT], M = -1e30f;
    #pragma unroll
    for (int s = 0; s < SPLIT; ++s) {
        ms[s] = Pm[(size_t)s * NROWS + row];
        ls[s] = Pl[(size_t)s * NROWS + row];
        M = fmaxf(M, ms[s]);
    }
    float wgt[SPLIT], den = 0.f;
    #pragma unroll
    for (int s = 0; s < SPLIT; ++s) {
        wgt[s] = __expf(ms[s] - M);
        den += wgt[s] * ls[s];
    }
    const float inv = 1.0f / den;

    float4 o[4];
    #pragma unroll
    for (int i = 0; i < 4; ++i) o[i] = make_float4(0.f, 0.f, 0.f, 0.f);
    #pragma unroll
    for (int s = 0; s < SPLIT; ++s) {
        const float4* a = (const float4*)(Pacc + ((size_t)s * NROWS + row) * 64 + quad * 16);
        #pragma unroll
        for (int i = 0; i < 4; ++i) {
            float4 v = a[i];
            o[i].x += wgt[s] * v.x; o[i].y += wgt[s] * v.y;
            o[i].z += wgt[s] * v.z; o[i].w += wgt[s] * v.w;
        }
    }
    float4* op = (float4*)(out + (size_t)row * 64 + quad * 16);
    #pragma unroll
    for (int i = 0; i < 4; ++i)
        op[i] = make_float4(o[i].x * inv, o[i].y * inv, o[i].z * inv, o[i].w * inv);
}

// ---------------------------------------------------------------------------
extern "C" void kernel_launch(void* const* d_in, const int* in_sizes, int n_in,
                              void* d_out, int out_size, void* d_ws, size_t ws_size,
                              hipStream_t stream) {
    const float* x  = (const float*)d_in[0];
    const float* Wq = (const float*)d_in[1];
    const float* Wk = (const float*)d_in[2];
    const float* Wv = (const float*)d_in[3];
    float* outp = (float*)d_out;

    float*  Qw   = (float*)d_ws;                        // 4 MB
    ushort* KhiP = (ushort*)(Qw + (size_t)NROWS * HH);  // 2 MB
    ushort* KloP = KhiP + (size_t)NROWS * HH;           // 2 MB
    ushort* VtP  = KloP + (size_t)NROWS * HH;           // 2 MB
    ushort* WpHi = VtP + (size_t)NROWS * HH;            // 384 KB
    ushort* WpLo = WpHi + (size_t)3 * 64 * 1024;        // 384 KB
    float*  Pacc = (float*)(WpLo + (size_t)3 * 64 * 1024);      // 16 MB
    float*  Pm   = Pacc + (size_t)SPLIT * NROWS * HH;           // 256 KB
    float*  Pl   = Pm + (size_t)SPLIT * NROWS;                  // 256 KB

    wprep_kernel<<<48, 256, 0, stream>>>(Wq, Wk, Wv, WpHi, WpLo);
    qkv_kernel<<<NROWS / 32, 256, 0, stream>>>(x, WpHi, WpLo, Qw, KhiP, KloP, VtP);
    attn_kernel<<<dim3(64 * SPLIT, BB), 128, 0, stream>>>(Qw, KhiP, KloP, VtP,
                                                          Pacc, Pm, Pl);
    combine_kernel<<<NROWS * 4 / 256, 256, 0, stream>>>(Pacc, Pm, Pl, outp);
}